// Round 2
// baseline (6284.592 us; speedup 1.0000x reference)
//
#include <hip/hip_runtime.h>
#include <hip/hip_bf16.h>

#define Bb 128
#define Tt 1024
#define Ii 64
#define Hh 128
#define XROW 896   // xi|xf|xc|xo (4*128) + aux0|aux1|aux2 (3*128)

static __device__ __forceinline__ float sigmoidf_(float x) {
  return 1.f / (1.f + expf(-x));
}

// ===========================================================================
// PATH 1 (needs 470MB workspace): proj kernel (256 CUs) + scan kernel.
// ===========================================================================
struct ProjArgs {
  const float* W[7];
  const float* bias[7];
};

__launch_bounds__(256, 2)
__global__ void proj_kernel(const float* __restrict__ Y,
                            const float* __restrict__ aux,
                            ProjArgs pa,
                            float* __restrict__ X) {
  const int w   = blockIdx.x;        // 4096 blocks
  const int b   = w >> 5;
  const int t0  = (w & 31) << 5;
  const int tau = threadIdx.x;

  __shared__ float inp[4][32][64];   // 32 KB
  __shared__ float wS[Ii][Hh];       // 32 KB

  {
    const float4* src = (const float4*)(Y + ((size_t)b * Tt + t0) * Ii);
    float4* dst = (float4*)&inp[0][0][0];
    dst[tau]       = src[tau];
    dst[tau + 256] = src[tau + 256];
  }
#pragma unroll
  for (int k3 = 0; k3 < 3; ++k3) {
    const float4* src = (const float4*)(aux + (((size_t)k3 * Bb + b) * Tt + t0) * Ii);
    float4* dst = (float4*)&inp[1 + k3][0][0];
    dst[tau]       = src[tau];
    dst[tau + 256] = src[tau + 256];
  }

  const int jg = tau & 31, rg = tau >> 5;
  const int j0 = jg * 4, r0 = rg * 4;

  for (int m = 0; m < 7; ++m) {
    __syncthreads();
    {
      const float4* src = (const float4*)pa.W[m];
      float4* dst = (float4*)&wS[0][0];
#pragma unroll
      for (int qq = 0; qq < 8; ++qq) dst[tau + qq * 256] = src[tau + qq * 256];
    }
    __syncthreads();

    const int srcI = (m < 4) ? 0 : (m - 3);
    const int off  = (m < 4) ? m * Hh : 512 + (m - 4) * Hh;

    float4 acc[4];
#pragma unroll
    for (int r = 0; r < 4; ++r) acc[r] = make_float4(0.f, 0.f, 0.f, 0.f);

#pragma unroll
    for (int kk = 0; kk < 16; ++kk) {
      float4 w0 = *(const float4*)&wS[kk * 4 + 0][j0];
      float4 w1 = *(const float4*)&wS[kk * 4 + 1][j0];
      float4 w2 = *(const float4*)&wS[kk * 4 + 2][j0];
      float4 w3 = *(const float4*)&wS[kk * 4 + 3][j0];
#pragma unroll
      for (int r = 0; r < 4; ++r) {
        float4 iv = *(const float4*)&inp[srcI][r0 + r][kk * 4];
        acc[r].x += iv.x * w0.x + iv.y * w1.x + iv.z * w2.x + iv.w * w3.x;
        acc[r].y += iv.x * w0.y + iv.y * w1.y + iv.z * w2.y + iv.w * w3.y;
        acc[r].z += iv.x * w0.z + iv.y * w1.z + iv.z * w2.z + iv.w * w3.z;
        acc[r].w += iv.x * w0.w + iv.y * w1.w + iv.z * w2.w + iv.w * w3.w;
      }
    }

    float4 bv = *(const float4*)(pa.bias[m] + j0);
#pragma unroll
    for (int r = 0; r < 4; ++r) {
      float4 o;
      o.x = acc[r].x + bv.x;  o.y = acc[r].y + bv.y;
      o.z = acc[r].z + bv.z;  o.w = acc[r].w + bv.w;
      if (m >= 4) { o.x = tanhf(o.x); o.y = tanhf(o.y); o.z = tanhf(o.z); o.w = tanhf(o.w); }
      *(float4*)&X[((size_t)(t0 + r0 + r) * Bb + b) * XROW + off + j0] = o;
    }
  }
}

__launch_bounds__(512, 2)
__global__ void scan_kernel(const float* __restrict__ X,
                            const float* __restrict__ Ui, const float* __restrict__ Uf,
                            const float* __restrict__ Uc, const float* __restrict__ Uo,
                            const float* __restrict__ Wa, const float* __restrict__ ba,
                            float* __restrict__ out) {
  const int b   = blockIdx.x;
  const int tau = threadIdx.x;
  const int j   = tau & 127;
  const int q   = tau >> 7;

  __shared__ float xbuf[2][XROW];
  __shared__ float hbuf[Hh];
  __shared__ float ctl[Hh];
  __shared__ float red[4][3][Hh];
  __shared__ float redA[4][3][Hh];

  float wU[4][32];
  {
    const float* Us[4] = {Ui, Uf, Uc, Uo};
#pragma unroll
    for (int g = 0; g < 4; ++g) {
#pragma unroll
      for (int k = 0; k < 32; ++k)
        wU[g][k] = Us[g][(q * 32 + k) * Hh + j];
    }
  }
  float wA[32];
#pragma unroll
  for (int k = 0; k < 32; ++k) wA[k] = Wa[(q * 32 + k) * Hh + j];
  const float ba_j = ba[j];

  if (tau < Hh) hbuf[tau] = 0.f;
  float c = 0.f;

  float2 xnext = make_float2(0.f, 0.f);
  if (tau < 448) xnext = ((const float2*)(X + (size_t)b * XROW))[tau];

  for (int t = 0; t < Tt; ++t) {
    const int p = t & 1;
    float2 xcur = xnext;
    if (tau < 448) *((float2*)&xbuf[p][tau * 2]) = xcur;
    if (tau < 448 && t + 1 < Tt)
      xnext = ((const float2*)(X + ((size_t)(t + 1) * Bb + b) * XROW))[tau];
    __syncthreads();  // B1

    float a0 = 0.f, a1 = 0.f, a2 = 0.f, a3 = 0.f;
#pragma unroll
    for (int kk = 0; kk < 8; ++kk) {
      float4 hv = *(const float4*)&hbuf[q * 32 + kk * 4];
      a0 += hv.x*wU[0][kk*4] + hv.y*wU[0][kk*4+1] + hv.z*wU[0][kk*4+2] + hv.w*wU[0][kk*4+3];
      a1 += hv.x*wU[1][kk*4] + hv.y*wU[1][kk*4+1] + hv.z*wU[1][kk*4+2] + hv.w*wU[1][kk*4+3];
      a2 += hv.x*wU[2][kk*4] + hv.y*wU[2][kk*4+1] + hv.z*wU[2][kk*4+2] + hv.w*wU[2][kk*4+3];
      a3 += hv.x*wU[3][kk*4] + hv.y*wU[3][kk*4+1] + hv.z*wU[3][kk*4+2] + hv.w*wU[3][kk*4+3];
    }
    if (q) {
      red[0][q-1][j] = a0; red[1][q-1][j] = a1;
      red[2][q-1][j] = a2; red[3][q-1][j] = a3;
    }
    __syncthreads();  // B2

    float ig = 0.f, fg = 0.f, og = 0.f;
    if (q == 0) {
      float pi = xbuf[p][j]       + a0 + red[0][0][j] + red[0][1][j] + red[0][2][j];
      float pf = xbuf[p][128 + j] + a1 + red[1][0][j] + red[1][1][j] + red[1][2][j];
      float pc = xbuf[p][256 + j] + a2 + red[2][0][j] + red[2][1][j] + red[2][2][j];
      float po = xbuf[p][384 + j] + a3 + red[3][0][j] + red[3][1][j] + red[3][2][j];
      ig = sigmoidf_(pi);
      fg = sigmoidf_(pf);
      og = sigmoidf_(po);
      ctl[j] = tanhf(pc);
    }
    __syncthreads();  // B3

    float s0 = 0.f, s1 = 0.f, s2 = 0.f, s3 = 0.f;
#pragma unroll
    for (int kk = 0; kk < 8; ++kk) {
      float4 c0 = *(const float4*)&ctl[q * 32 + kk * 4];
      float4 c1 = *(const float4*)&xbuf[p][512 + q * 32 + kk * 4];
      float4 c2 = *(const float4*)&xbuf[p][640 + q * 32 + kk * 4];
      float4 c3 = *(const float4*)&xbuf[p][768 + q * 32 + kk * 4];
      s0 += c0.x*wA[kk*4] + c0.y*wA[kk*4+1] + c0.z*wA[kk*4+2] + c0.w*wA[kk*4+3];
      s1 += c1.x*wA[kk*4] + c1.y*wA[kk*4+1] + c1.z*wA[kk*4+2] + c1.w*wA[kk*4+3];
      s2 += c2.x*wA[kk*4] + c2.y*wA[kk*4+1] + c2.z*wA[kk*4+2] + c2.w*wA[kk*4+3];
      s3 += c3.x*wA[kk*4] + c3.y*wA[kk*4+1] + c3.z*wA[kk*4+2] + c3.w*wA[kk*4+3];
    }
    if (q) {
      redA[0][q-1][j] = s0; redA[1][q-1][j] = s1;
      redA[2][q-1][j] = s2; redA[3][q-1][j] = s3;
    }
    __syncthreads();  // B4

    if (q == 0) {
      float v0 = ba_j + s0 + redA[0][0][j] + redA[0][1][j] + redA[0][2][j];
      float v1 = ba_j + s1 + redA[1][0][j] + redA[1][1][j] + redA[1][2][j];
      float v2 = ba_j + s2 + redA[2][0][j] + redA[2][1][j] + redA[2][2][j];
      float v3 = ba_j + s3 + redA[3][0][j] + redA[3][1][j] + redA[3][2][j];
      float mx = fmaxf(fmaxf(v0, v1), fmaxf(v2, v3));
      float e0 = expf(v0 - mx), e1 = expf(v1 - mx), e2 = expf(v2 - mx), e3 = expf(v3 - mx);
      float inv = 1.f / (e0 + e1 + e2 + e3);
      float L = (e0 * ctl[j] + e1 * xbuf[p][512 + j] + e2 * xbuf[p][640 + j]
                 + e3 * xbuf[p][768 + j]) * inv;
      c = fg * c + ig * L;
      float h = og * tanhf(c);
      hbuf[j] = h;
      out[16384 + ((size_t)b * Tt + t) * Hh + j] = h;
      if (t == Tt - 1) out[(size_t)b * Hh + j] = h;
    }
  }
}

// ===========================================================================
// PATH 2 (workspace-free): fully fused persistent scan.
// 128 blocks (one per batch row) x 512 threads.  Thread (j = tau&127,
// q = tau>>7).  Recurrent weights in registers; input-proj gate weights in
// LDS (128KB); aux-proj + softmax-gate weights in registers.
// ===========================================================================
__launch_bounds__(512, 2)
__global__ void fused_kernel(const float* __restrict__ Y,
                             const float* __restrict__ aux,
                             const float* __restrict__ Wi, const float* __restrict__ Ui,
                             const float* __restrict__ bi,
                             const float* __restrict__ Wf, const float* __restrict__ Uf,
                             const float* __restrict__ bfp,
                             const float* __restrict__ Wc, const float* __restrict__ Uc,
                             const float* __restrict__ bc,
                             const float* __restrict__ Wo, const float* __restrict__ Uo,
                             const float* __restrict__ bo,
                             const float* __restrict__ auxW, const float* __restrict__ auxb,
                             const float* __restrict__ Wa, const float* __restrict__ ba,
                             float* __restrict__ out) {
  const int b   = blockIdx.x;
  const int tau = threadIdx.x;
  const int j   = tau & 127;
  const int q   = tau >> 7;

  __shared__ float wG[4][Ii][Hh];      // 128 KB: W_i|W_f|W_c|W_o, [k][j]
  __shared__ float xraw[2][4][Ii];     // 2 KB: Y row + 3 aux rows, dbuf
  __shared__ float hbuf[Hh];
  __shared__ float ctl[Hh];
  __shared__ float auxp[3][Hh];
  __shared__ float redG[4][4][Hh];     // 8 KB: gate partials / softmax partials
  __shared__ float redX[3][4][Hh];     // 6 KB: aux partials

  // ---- load weights ----
  float wU[4][32];
  {
    const float* Us[4] = {Ui, Uf, Uc, Uo};
#pragma unroll
    for (int g = 0; g < 4; ++g) {
#pragma unroll
      for (int k = 0; k < 32; ++k)
        wU[g][k] = Us[g][(q * 32 + k) * Hh + j];
    }
  }
  float wA[32];
#pragma unroll
  for (int k = 0; k < 32; ++k) wA[k] = Wa[(q * 32 + k) * Hh + j];

  float wAux[3][16];
#pragma unroll
  for (int m = 0; m < 3; ++m) {
#pragma unroll
    for (int k = 0; k < 16; ++k)
      wAux[m][k] = auxW[((size_t)m * Ii + (q * 16 + k)) * Hh + j];
  }

  float bgate[4];
  {
    const float* Bs[4] = {bi, bfp, bc, bo};
#pragma unroll
    for (int g = 0; g < 4; ++g) bgate[g] = Bs[g][j];
  }
  const float abias = (q >= 1) ? auxb[(q - 1) * Hh + j] : 0.f;
  const float ba_j  = ba[j];

  // ---- stage input-proj gate weights into LDS (4 x 8192 floats) ----
  {
    const float* Ws[4] = {Wi, Wf, Wc, Wo};
#pragma unroll
    for (int g = 0; g < 4; ++g) {
      const float4* src = (const float4*)Ws[g];
      float4* dst = (float4*)&wG[g][0][0];
#pragma unroll
      for (int r = 0; r < 4; ++r) dst[tau + r * 512] = src[tau + r * 512];
    }
  }

  if (tau < Hh) hbuf[tau] = 0.f;
  float c = 0.f;

  // ---- raw-input prefetch machinery: wave 0 (tau<64) handles 256 floats ----
  const bool ldr = (tau < 64);
  const int  m4  = tau >> 4;       // 0=Y, 1..3=aux factor
  const int  idx = tau & 15;       // float4 slot within 64-float row
  const float* srcbase = nullptr;
  float4 xn = make_float4(0.f, 0.f, 0.f, 0.f);
  if (ldr) {
    srcbase = (m4 == 0) ? (Y + ((size_t)b * Tt) * Ii)
                        : (aux + (((size_t)(m4 - 1) * Bb + b) * Tt) * Ii);
    // t = 0 row
    float4 x0 = ((const float4*)srcbase)[idx];
    ((float4*)&xraw[0][0][0])[tau] = x0;
    // prefetch t = 1
    xn = ((const float4*)(srcbase + Ii))[idx];
  }
  __syncthreads();  // weights + hbuf + xraw[0] ready

  for (int t = 0; t < Tt; ++t) {
    const int p = t & 1;

    // ================= Phase A: gate + aux partials =================
    float aG0 = 0.f, aG1 = 0.f, aG2 = 0.f, aG3 = 0.f;
#pragma unroll
    for (int kk = 0; kk < 8; ++kk) {
      float4 hv = *(const float4*)&hbuf[q * 32 + kk * 4];
      aG0 += hv.x*wU[0][kk*4] + hv.y*wU[0][kk*4+1] + hv.z*wU[0][kk*4+2] + hv.w*wU[0][kk*4+3];
      aG1 += hv.x*wU[1][kk*4] + hv.y*wU[1][kk*4+1] + hv.z*wU[1][kk*4+2] + hv.w*wU[1][kk*4+3];
      aG2 += hv.x*wU[2][kk*4] + hv.y*wU[2][kk*4+1] + hv.z*wU[2][kk*4+2] + hv.w*wU[2][kk*4+3];
      aG3 += hv.x*wU[3][kk*4] + hv.y*wU[3][kk*4+1] + hv.z*wU[3][kk*4+2] + hv.w*wU[3][kk*4+3];
    }
    // input projection: k in [16q, 16q+16) of the 64-wide Y row
#pragma unroll
    for (int kk = 0; kk < 4; ++kk) {
      const int k0 = q * 16 + kk * 4;
      float4 yv = *(const float4*)&xraw[p][0][k0];
      aG0 += yv.x*wG[0][k0][j] + yv.y*wG[0][k0+1][j] + yv.z*wG[0][k0+2][j] + yv.w*wG[0][k0+3][j];
      aG1 += yv.x*wG[1][k0][j] + yv.y*wG[1][k0+1][j] + yv.z*wG[1][k0+2][j] + yv.w*wG[1][k0+3][j];
      aG2 += yv.x*wG[2][k0][j] + yv.y*wG[2][k0+1][j] + yv.z*wG[2][k0+2][j] + yv.w*wG[2][k0+3][j];
      aG3 += yv.x*wG[3][k0][j] + yv.y*wG[3][k0+1][j] + yv.z*wG[3][k0+2][j] + yv.w*wG[3][k0+3][j];
    }
    float sA0 = 0.f, sA1 = 0.f, sA2 = 0.f;
#pragma unroll
    for (int kk = 0; kk < 4; ++kk) {
      const int k0 = q * 16 + kk * 4;
      float4 a0v = *(const float4*)&xraw[p][1][k0];
      float4 a1v = *(const float4*)&xraw[p][2][k0];
      float4 a2v = *(const float4*)&xraw[p][3][k0];
      sA0 += a0v.x*wAux[0][kk*4] + a0v.y*wAux[0][kk*4+1] + a0v.z*wAux[0][kk*4+2] + a0v.w*wAux[0][kk*4+3];
      sA1 += a1v.x*wAux[1][kk*4] + a1v.y*wAux[1][kk*4+1] + a1v.z*wAux[1][kk*4+2] + a1v.w*wAux[1][kk*4+3];
      sA2 += a2v.x*wAux[2][kk*4] + a2v.y*wAux[2][kk*4+1] + a2v.z*wAux[2][kk*4+2] + a2v.w*wAux[2][kk*4+3];
    }
    redG[0][q][j] = aG0;  redG[1][q][j] = aG1;
    redG[2][q][j] = aG2;  redG[3][q][j] = aG3;
    redX[0][q][j] = sA0;  redX[1][q][j] = sA1;  redX[2][q][j] = sA2;
    __syncthreads();  // B1

    // ================= Phase B: activations (distributed) ===========
    float ig = 0.f, fg = 0.f, og = 0.f;
    if (q == 0) {
      float pi = bgate[0] + redG[0][0][j] + redG[0][1][j] + redG[0][2][j] + redG[0][3][j];
      float pf = bgate[1] + redG[1][0][j] + redG[1][1][j] + redG[1][2][j] + redG[1][3][j];
      float pc = bgate[2] + redG[2][0][j] + redG[2][1][j] + redG[2][2][j] + redG[2][3][j];
      float po = bgate[3] + redG[3][0][j] + redG[3][1][j] + redG[3][2][j] + redG[3][3][j];
      ig = sigmoidf_(pi);
      fg = sigmoidf_(pf);
      og = sigmoidf_(po);
      ctl[j] = tanhf(pc);
    } else {
      const int m = q - 1;
      float v = abias + redX[m][0][j] + redX[m][1][j] + redX[m][2][j] + redX[m][3][j];
      auxp[m][j] = tanhf(v);
    }
    // staging slot: write x(t+1) into the other buffer; prefetch x(t+2)
    if (ldr) {
      ((float4*)&xraw[p ^ 1][0][0])[tau] = xn;
      if (t + 2 < Tt) xn = ((const float4*)(srcbase + (size_t)(t + 2) * Ii))[idx];
    }
    __syncthreads();  // B2

    // ================= Phase C: softmax-gate matvec =================
    float sS0 = 0.f, sS1 = 0.f, sS2 = 0.f, sS3 = 0.f;
#pragma unroll
    for (int kk = 0; kk < 8; ++kk) {
      const int k0 = q * 32 + kk * 4;
      float4 c0 = *(const float4*)&ctl[k0];
      float4 c1 = *(const float4*)&auxp[0][k0];
      float4 c2 = *(const float4*)&auxp[1][k0];
      float4 c3 = *(const float4*)&auxp[2][k0];
      sS0 += c0.x*wA[kk*4] + c0.y*wA[kk*4+1] + c0.z*wA[kk*4+2] + c0.w*wA[kk*4+3];
      sS1 += c1.x*wA[kk*4] + c1.y*wA[kk*4+1] + c1.z*wA[kk*4+2] + c1.w*wA[kk*4+3];
      sS2 += c2.x*wA[kk*4] + c2.y*wA[kk*4+1] + c2.z*wA[kk*4+2] + c2.w*wA[kk*4+3];
      sS3 += c3.x*wA[kk*4] + c3.y*wA[kk*4+1] + c3.z*wA[kk*4+2] + c3.w*wA[kk*4+3];
    }
    redG[0][q][j] = sS0;  redG[1][q][j] = sS1;
    redG[2][q][j] = sS2;  redG[3][q][j] = sS3;
    __syncthreads();  // B3

    // ================= Phase D: softmax + cell update ===============
    if (q == 0) {
      float v0 = ba_j + redG[0][0][j] + redG[0][1][j] + redG[0][2][j] + redG[0][3][j];
      float v1 = ba_j + redG[1][0][j] + redG[1][1][j] + redG[1][2][j] + redG[1][3][j];
      float v2 = ba_j + redG[2][0][j] + redG[2][1][j] + redG[2][2][j] + redG[2][3][j];
      float v3 = ba_j + redG[3][0][j] + redG[3][1][j] + redG[3][2][j] + redG[3][3][j];
      float mx = fmaxf(fmaxf(v0, v1), fmaxf(v2, v3));
      float e0 = expf(v0 - mx), e1 = expf(v1 - mx), e2 = expf(v2 - mx), e3 = expf(v3 - mx);
      float inv = 1.f / (e0 + e1 + e2 + e3);
      float L = (e0 * ctl[j] + e1 * auxp[0][j] + e2 * auxp[1][j] + e3 * auxp[2][j]) * inv;
      c = fg * c + ig * L;
      float h = og * tanhf(c);
      hbuf[j] = h;
      out[16384 + ((size_t)b * Tt + t) * Hh + j] = h;
      if (t == Tt - 1) out[(size_t)b * Hh + j] = h;
    }
    __syncthreads();  // B4: hbuf stable before next Phase A
  }
}

// ===========================================================================
extern "C" void kernel_launch(void* const* d_in, const int* in_sizes, int n_in,
                              void* d_out, int out_size, void* d_ws, size_t ws_size,
                              hipStream_t stream) {
  (void)in_sizes; (void)n_in; (void)out_size;
  const float* Y     = (const float*)d_in[0];
  const float* aux   = (const float*)d_in[1];
  const float* W_i   = (const float*)d_in[2];
  const float* U_i   = (const float*)d_in[3];
  const float* b_i   = (const float*)d_in[4];
  const float* W_f   = (const float*)d_in[5];
  const float* U_f   = (const float*)d_in[6];
  const float* b_f   = (const float*)d_in[7];
  const float* W_c   = (const float*)d_in[8];
  const float* U_c   = (const float*)d_in[9];
  const float* b_c   = (const float*)d_in[10];
  const float* W_o   = (const float*)d_in[11];
  const float* U_o   = (const float*)d_in[12];
  const float* b_o   = (const float*)d_in[13];
  const float* aux_W = (const float*)d_in[14];
  const float* aux_b = (const float*)d_in[15];
  const float* W_a   = (const float*)d_in[16];
  const float* b_a   = (const float*)d_in[17];

  float* out = (float*)d_out;

  const size_t X_BYTES = (size_t)Tt * Bb * XROW * sizeof(float);  // 470 MB

  if (d_ws != nullptr && ws_size >= X_BYTES) {
    // -------- PATH 1: precompute projections to workspace, then scan ------
    float* X = (float*)d_ws;
    ProjArgs pa;
    pa.W[0] = W_i;  pa.W[1] = W_f;  pa.W[2] = W_c;  pa.W[3] = W_o;
    pa.W[4] = aux_W;
    pa.W[5] = aux_W + 64 * 128;
    pa.W[6] = aux_W + 2 * 64 * 128;
    pa.bias[0] = b_i;  pa.bias[1] = b_f;  pa.bias[2] = b_c;  pa.bias[3] = b_o;
    pa.bias[4] = aux_b;  pa.bias[5] = aux_b + 128;  pa.bias[6] = aux_b + 256;

    proj_kernel<<<dim3(4096), dim3(256), 0, stream>>>(Y, aux, pa, X);
    scan_kernel<<<dim3(128), dim3(512), 0, stream>>>(X, U_i, U_f, U_c, U_o, W_a, b_a, out);
  } else {
    // -------- PATH 2: fully fused, workspace-free -------------------------
    fused_kernel<<<dim3(128), dim3(512), 0, stream>>>(
        Y, aux,
        W_i, U_i, b_i,
        W_f, U_f, b_f,
        W_c, U_c, b_c,
        W_o, U_o, b_o,
        aux_W, aux_b, W_a, b_a, out);
  }
}